// Round 8
// baseline (74460.052 us; speedup 1.0000x reference)
//
#include <hip/hip_runtime.h>
#include <cstdint>

// DROP_MODE 3 = JAX partitionable threefry, bits = x0^x1  (VERIFIED r3+: absmax 0.0039)

static constexpr int TDEC = 400, TENC = 300, NMEL = 80, NBLK = 256;
static constexpr int RING = 4;

__device__ __forceinline__ uint2 threefry2x32(uint32_t k0, uint32_t k1,
                                              uint32_t x0, uint32_t x1) {
  uint32_t k2 = k0 ^ k1 ^ 0x1BD11BDAu;
  x0 += k0; x1 += k1;
#define TFR(r) { x0 += x1; x1 = (x1 << (r)) | (x1 >> (32 - (r))); x1 ^= x0; }
  TFR(13) TFR(15) TFR(26) TFR(6)
  x0 += k1; x1 += k2 + 1u;
  TFR(17) TFR(29) TFR(16) TFR(24)
  x0 += k2; x1 += k0 + 2u;
  TFR(13) TFR(15) TFR(26) TFR(6)
  x0 += k0; x1 += k1 + 3u;
  TFR(17) TFR(29) TFR(16) TFR(24)
  x0 += k1; x1 += k2 + 4u;
  TFR(13) TFR(15) TFR(26) TFR(6)
  x0 += k2; x1 += k0 + 5u;
#undef TFR
  return make_uint2(x0, x1);
}

__device__ __forceinline__ bool keep_mask(uint32_t key0, uint32_t key1, uint32_t idx) {
  uint2 o = threefry2x32(key0, key1, 0u, idx);
  uint32_t bits = o.x ^ o.y;
  float u = __uint_as_float((bits >> 9) | 0x3f800000u) - 1.0f;
  return u < 0.5f;
}

__device__ __forceinline__ float dot4(float4 w, float4 a) {
  return w.x * a.x + w.y * a.y + w.z * a.z + w.w * a.w;
}

__device__ __forceinline__ void s_rel(float* p, float v) {
  __hip_atomic_store(p, v, __ATOMIC_RELAXED, __HIP_MEMORY_SCOPE_AGENT);
}
__device__ __forceinline__ float l_rel(const float* p) {
  return __hip_atomic_load(p, __ATOMIC_RELAXED, __HIP_MEMORY_SCOPE_AGENT);
}
__device__ __forceinline__ float nt_load(const float* p) {
  return __builtin_nontemporal_load(p);
}

// ---- 16-member group barrier (relaxed flags; NO cache invalidation ever) ----
__device__ __forceinline__ void rsync16(int* garr, int* grel, int g, int s, int val) {
  __syncthreads();
  if (s == 0) {
    if (threadIdx.x < 15)
      while (__hip_atomic_load(&garr[(g * 16 + 1 + threadIdx.x) * 32], __ATOMIC_RELAXED,
                               __HIP_MEMORY_SCOPE_AGENT) < val)
        __builtin_amdgcn_s_sleep(8);
    __syncthreads();
    if (threadIdx.x == 0)
      __hip_atomic_store(&grel[g * 32], val, __ATOMIC_RELEASE, __HIP_MEMORY_SCOPE_AGENT);
  } else {
    if (threadIdx.x == 0) {
      __hip_atomic_store(&garr[(g * 16 + s) * 32], val, __ATOMIC_RELEASE,
                         __HIP_MEMORY_SCOPE_AGENT);
      while (__hip_atomic_load(&grel[g * 32], __ATOMIC_RELAXED,
                               __HIP_MEMORY_SCOPE_AGENT) < val)
        __builtin_amdgcn_s_sleep(8);
    }
  }
  __syncthreads();
}

// ---- prenet (teacher-forced, all 400 steps parallel; verified) --------------
template <int K>
__device__ __forceinline__ void prenet_layer(const float* in_lds, float* out_lds,
                                             float* out_g, const float* __restrict__ W,
                                             uint32_t key0, uint32_t key1, int b0) {
  const int tid = threadIdx.x;
  const int cgp = tid & 63, bg = tid >> 6;
  float acc[4][4];
#pragma unroll
  for (int cc = 0; cc < 4; ++cc)
#pragma unroll
    for (int rr = 0; rr < 4; ++rr) acc[cc][rr] = 0.f;
  const float4* W4 = (const float4*)W;
  const float4* in4 = (const float4*)in_lds;
  for (int k4 = 0; k4 < K / 4; ++k4) {
    float4 a[4];
#pragma unroll
    for (int rr = 0; rr < 4; ++rr) a[rr] = in4[(bg * 4 + rr) * (K / 4) + k4];
#pragma unroll
    for (int cc = 0; cc < 4; ++cc) {
      float4 w = W4[(cgp + 64 * cc) * (K / 4) + k4];
#pragma unroll
      for (int rr = 0; rr < 4; ++rr) acc[cc][rr] += dot4(w, a[rr]);
    }
  }
#pragma unroll
  for (int cc = 0; cc < 4; ++cc)
#pragma unroll
    for (int rr = 0; rr < 4; ++rr) {
      int c = cgp + 64 * cc, br = bg * 4 + rr;
      float val = fmaxf(acc[cc][rr], 0.f);
      val = keep_mask(key0, key1, (uint32_t)((b0 + br) * 256 + c)) ? val * 2.f : 0.f;
      if (out_lds) out_lds[br * 256 + c] = val;
      if (out_g) out_g[(b0 + br) * 256 + c] = val;
    }
  __syncthreads();
}

__global__ __launch_bounds__(256) void prenet_kernel(const float* __restrict__ mels,
                                                     const float* __restrict__ Wp0,
                                                     const float* __restrict__ Wp1,
                                                     const float* __restrict__ Wp2,
                                                     float* __restrict__ x_all) {
  __shared__ float bufA[16 * 256];
  __shared__ float bufB[16 * 256];
  const int t = blockIdx.x >> 1, b0 = (blockIdx.x & 1) * 16;
  const int tid = threadIdx.x;
  for (int i = tid; i < 16 * 80; i += 256) {
    int br = i / 80, k = i % 80;
    bufB[br * 80 + k] = (t == 0) ? 0.f : mels[((b0 + br) * TDEC + (t - 1)) * NMEL + k];
  }
  __syncthreads();
  uint2 k0v = threefry2x32(0u, 42u, 0u, (uint32_t)(t * 3 + 0));
  uint2 k1v = threefry2x32(0u, 42u, 0u, (uint32_t)(t * 3 + 1));
  uint2 k2v = threefry2x32(0u, 42u, 0u, (uint32_t)(t * 3 + 2));
  prenet_layer<80>(bufB, bufA, nullptr, Wp0, k0v.x, k0v.y, b0);
  prenet_layer<256>(bufA, bufB, nullptr, Wp1, k1v.x, k1v.y, b0);
  prenet_layer<256>(bufB, nullptr, x_all + t * 8192, Wp2, k2v.x, k2v.y, b0);
}

// ---- pmem = enc @ Wm.T (unchanged) ------------------------------------------
__global__ __launch_bounds__(256) void pmem_kernel(const float* __restrict__ enc,
                                                   const float* __restrict__ Wm,
                                                   float* __restrict__ pmem) {
  const int b = blockIdx.x / 10, pc = blockIdx.x % 10;
  const int j = threadIdx.x & 127, ph = threadIdx.x >> 7;
  const float4* Wm4 = (const float4*)Wm;
  const float4* enc4 = (const float4*)enc + (size_t)(b * 300 + pc * 30 + ph * 15) * 128;
  float acc[15];
#pragma unroll
  for (int pp = 0; pp < 15; ++pp) acc[pp] = 0.f;
  for (int k4 = 0; k4 < 128; ++k4) {
    float4 w = Wm4[j * 128 + k4];
#pragma unroll
    for (int pp = 0; pp < 15; ++pp) acc[pp] += dot4(w, enc4[pp * 128 + k4]);
  }
#pragma unroll
  for (int pp = 0; pp < 15; ++pp)
    pmem[(size_t)(b * 300 + pc * 30 + ph * 15 + pp) * 128 + j] = acc[pp];
}

// ---- persistent decoder: 16 groups x 16 slices; all mutable state via LLC ---
struct DecParams {
  const float* enc; const float* xall; const float* pmem;
  const int* lens;
  const float *Wiha, *Whha, *biha, *bhha;
  const float *Wihd, *Whhd, *bihd, *bhhd;
  const float *Wq, *Kloc, *Wl, *vv, *Wout, *bout, *Wg, *bg;
  float *ah, *dh, *ctx, *e;
  int *garr, *grel;
  float *omel, *ogate, *oalign;
};

#define PAW 7000
#define PT2 8320
#define PCV 10304

__global__ __launch_bounds__(256) void decoder_kernel(DecParams P) {
  __shared__ float smem[11600];
  const int blk = blockIdx.x, tid = threadIdx.x;
  const int g = blk >> 4, s = blk & 15;
  const int r0 = 2 * g;
  float2* aw2 = (float2*)(smem + PAW);   // [ri][330], halo 15 each side
  float2* t2f = (float2*)(smem + PT2);
  float* conv_l = smem + PCV;            // [ri][32][20]
  const int pb = s * 19, pc = min(19, TENC - pb);
  int bno = 0;

  for (int i = tid; i < 660; i += 256) aw2[i] = make_float2(0.f, 0.f);
  for (int i = tid; i < 992; i += 256) {
    int f = i / 31, k = i % 31;
    t2f[i] = make_float2(P.Kloc[f * 62 + k], P.Kloc[f * 62 + 31 + k]);
  }
  const int lane = tid & 63;
  const float vv0 = P.vv[lane], vv1 = P.vv[lane + 64];
  __syncthreads();

  for (int tt = 0; tt <= TDEC; ++tt) {
    const int sc = tt & (RING - 1), s1 = (tt - 1) & (RING - 1), s2 = (tt - 2) & (RING - 1);
    float* ahC = P.ah + sc * 16384;
    const float* ahP = P.ah + s1 * 16384;
    const float* ctxP = P.ctx + s1 * 16384;
    float* dhW = P.dh + s1 * 16384;
    const float* dhP = P.dh + s2 * 16384;

    // ---- conv_t from LDS aw-state (t-1), block's position slice ----
    if (tt < TDEC) {
      int f = tid >> 3, po0 = tid & 7;
      for (int po = po0; po < pc; po += 8) {
        int p = pb + po;
        float a0 = 0.f, a1 = 0.f;
#pragma unroll
        for (int k = 0; k < 31; ++k) {
          float2 t = t2f[f * 31 + k];
          float2 v0 = aw2[p + k];
          float2 v1 = aw2[330 + p + k];
          a0 += v0.x * t.x + v0.y * t.y;
          a1 += v1.x * t.x + v1.y * t.y;
        }
        conv_l[(0 * 32 + f) * 20 + po] = a0;
        conv_l[(1 * 32 + f) * 20 + po] = a1;
      }
    }

    // ---- stage S1 (state via batched bypass loads; xall cacheable) ----
    float* xS = smem;
    float* cS = smem + 512;
    float* hS = smem + 1536;
    float* dS = smem + 2560;
    {
      float rc[4], rh[4], rd[4];
#pragma unroll
      for (int j = 0; j < 4; ++j) {
        int i = tid + j * 256;
        int ri = i >> 9, k = i & 511;
        int off = (r0 + ri) * 512 + k;
        rc[j] = l_rel(&ctxP[off]);
        rh[j] = l_rel(&ahP[off]);
        rd[j] = l_rel(&dhP[off]);
      }
      for (int i = tid; i < 512; i += 256) {
        int ri = i >> 8, k = i & 255;
        xS[i] = (tt < TDEC) ? P.xall[(size_t)tt * 8192 + (r0 + ri) * 256 + k] : 0.f;
      }
#pragma unroll
      for (int j = 0; j < 4; ++j) {
        int i = tid + j * 256;
        cS[i] = rc[j]; hS[i] = rh[j]; dS[i] = rd[j];
      }
    }
    __syncthreads();

    const float4* xS4 = (const float4*)xS;
    const float4* cS4 = (const float4*)cS;
    const float4* hS4 = (const float4*)hS;
    const float4* dS4 = (const float4*)dS;
    const int ii = tid >> 3, ks = tid & 7;

    // ---- attGRU_t: h-slice [s*32, s*32+32), both rows; shfl reduce ----
    if (tt < TDEC) {
      float acc[2][6];
#pragma unroll
      for (int ri = 0; ri < 2; ++ri)
#pragma unroll
        for (int a = 0; a < 6; ++a) acc[ri][a] = 0.f;
      const float4* Wih4 = (const float4*)P.Wiha;
      const float4* Whh4 = (const float4*)P.Whha;
#pragma unroll
      for (int gate = 0; gate < 3; ++gate) {
        int wrow = gate * 512 + s * 32 + ii;
        const float4* wi = Wih4 + (size_t)wrow * 192;
        for (int k4 = ks * 24; k4 < ks * 24 + 24; ++k4) {
          float4 w = wi[k4];
          float4 a0 = (k4 < 64) ? xS4[k4] : cS4[k4 - 64];
          float4 a1 = (k4 < 64) ? xS4[64 + k4] : cS4[128 + (k4 - 64)];
          acc[0][gate] += dot4(w, a0);
          acc[1][gate] += dot4(w, a1);
        }
        const float4* wh = Whh4 + (size_t)wrow * 128;
        for (int k4 = ks * 16; k4 < ks * 16 + 16; ++k4) {
          float4 w = wh[k4];
          acc[0][3 + gate] += dot4(w, hS4[k4]);
          acc[1][3 + gate] += dot4(w, hS4[128 + k4]);
        }
      }
#pragma unroll
      for (int ri = 0; ri < 2; ++ri)
#pragma unroll
        for (int a = 0; a < 6; ++a) {
          float v = acc[ri][a];
          v += __shfl_xor(v, 1, 64);
          v += __shfl_xor(v, 2, 64);
          v += __shfl_xor(v, 4, 64);
          acc[ri][a] = v;
        }
      if (ks == 0) {
        int hi = s * 32 + ii;
#pragma unroll
        for (int ri = 0; ri < 2; ++ri) {
          float gir = acc[ri][0] + P.biha[hi], giz = acc[ri][1] + P.biha[512 + hi],
                gin = acc[ri][2] + P.biha[1024 + hi];
          float ghr = acc[ri][3] + P.bhha[hi], ghz = acc[ri][4] + P.bhha[512 + hi],
                ghn = acc[ri][5] + P.bhha[1024 + hi];
          float rr = 1.f / (1.f + expf(-(gir + ghr)));
          float zz = 1.f / (1.f + expf(-(giz + ghz)));
          float nn = tanhf(gin + rr * ghn);
          float hp = hS[ri * 512 + hi];
          s_rel(&ahC[(r0 + ri) * 512 + hi], (1.f - zz) * nn + zz * hp);
        }
      }
    }

    // ---- decGRU_{t-1}: input [ah_{t-1} | ctx_{t-1}], hprev dh_{t-2} ----
    if (tt >= 1) {
      float acc[2][6];
#pragma unroll
      for (int ri = 0; ri < 2; ++ri)
#pragma unroll
        for (int a = 0; a < 6; ++a) acc[ri][a] = 0.f;
      const float4* Wih4 = (const float4*)P.Wihd;
      const float4* Whh4 = (const float4*)P.Whhd;
#pragma unroll
      for (int gate = 0; gate < 3; ++gate) {
        int wrow = gate * 512 + s * 32 + ii;
        const float4* wi = Wih4 + (size_t)wrow * 256;
        for (int k4 = ks * 32; k4 < ks * 32 + 32; ++k4) {
          float4 w = wi[k4];
          float4 a0 = (k4 < 128) ? hS4[k4] : cS4[k4 - 128];
          float4 a1 = (k4 < 128) ? hS4[128 + k4] : cS4[128 + (k4 - 128)];
          acc[0][gate] += dot4(w, a0);
          acc[1][gate] += dot4(w, a1);
        }
        const float4* wh = Whh4 + (size_t)wrow * 128;
        for (int k4 = ks * 16; k4 < ks * 16 + 16; ++k4) {
          float4 w = wh[k4];
          acc[0][3 + gate] += dot4(w, dS4[k4]);
          acc[1][3 + gate] += dot4(w, dS4[128 + k4]);
        }
      }
#pragma unroll
      for (int ri = 0; ri < 2; ++ri)
#pragma unroll
        for (int a = 0; a < 6; ++a) {
          float v = acc[ri][a];
          v += __shfl_xor(v, 1, 64);
          v += __shfl_xor(v, 2, 64);
          v += __shfl_xor(v, 4, 64);
          acc[ri][a] = v;
        }
      if (ks == 0) {
        int hi = s * 32 + ii;
#pragma unroll
        for (int ri = 0; ri < 2; ++ri) {
          float gir = acc[ri][0] + P.bihd[hi], giz = acc[ri][1] + P.bihd[512 + hi],
                gin = acc[ri][2] + P.bihd[1024 + hi];
          float ghr = acc[ri][3] + P.bhhd[hi], ghz = acc[ri][4] + P.bhhd[512 + hi],
                ghn = acc[ri][5] + P.bhhd[1024 + hi];
          float rr = 1.f / (1.f + expf(-(gir + ghr)));
          float zz = 1.f / (1.f + expf(-(giz + ghz)));
          float nn = tanhf(gin + rr * ghn);
          float hp = dS[ri * 512 + hi];
          s_rel(&dhW[(r0 + ri) * 512 + hi], (1.f - zz) * nn + zz * hp);
        }
      }
    }
    rsync16(P.garr, P.grel, g, s, ++bno);  // SYNC1

    // ---- phase D: restage; q-proj; outproj(tt-1); energies ----
    {
      float* ahS = smem;          // [2][512]
      float* dS2 = smem + 1024;   // [2][512]
      float* cS2 = smem + 2048;   // [2][512]
      {
        float ra[4], rd2[4], rc2[4];
#pragma unroll
        for (int j = 0; j < 4; ++j) {
          int i = tid + j * 256;
          int ri = i >> 9, k = i & 511;
          int off = (r0 + ri) * 512 + k;
          ra[j] = (tt < TDEC) ? l_rel(&ahC[off]) : 0.f;
          rd2[j] = l_rel(&dhW[off]);
          rc2[j] = l_rel(&ctxP[off]);
        }
#pragma unroll
        for (int j = 0; j < 4; ++j) {
          int i = tid + j * 256;
          ahS[i] = ra[j]; dS2[i] = rd2[j]; cS2[i] = rc2[j];
        }
      }
      __syncthreads();
      float* qb = smem + 3072;        // [2][128]
      float* op = smem + 3328;        // [96]
      if (tt < TDEC) {
        int ri = tid >> 7, qi = tid & 127;
        const float4* Wq4 = (const float4*)P.Wq;
        const float4* a4 = (const float4*)ahS + ri * 128;
        float acc = 0.f;
        for (int k4 = 0; k4 < 128; ++k4) acc += dot4(Wq4[qi * 128 + k4], a4[k4]);
        qb[ri * 128 + qi] = acc;
      }
      if (tt >= 1) {
        for (int u = tid; u < 96; u += 256) {
          int mi = u / 16, ri = (u >> 3) & 1, kq = u & 7;
          int m = s + 16 * mi;
          if (m <= 80) {
            const float4* W4 = (m < 80) ? ((const float4*)P.Wout + (size_t)m * 256)
                                        : (const float4*)P.Wg;
            const float4* dh4 = (const float4*)dS2 + ri * 128;
            const float4* cx4 = (const float4*)cS2 + ri * 128;
            float a = 0.f;
            for (int k4 = kq * 32; k4 < kq * 32 + 32; ++k4) {
              float4 x = (k4 < 128) ? dh4[k4] : cx4[k4 - 128];
              a += dot4(W4[k4], x);
            }
            op[u] = a;
          }
        }
      }
      __syncthreads();
      if (tt >= 1 && tid < 12) {
        int mi = tid >> 1, ri = tid & 1;
        int m = s + 16 * mi;
        if (m <= 80 && (m < 80 || s == 0)) {
          float sum = 0.f;
#pragma unroll
          for (int k = 0; k < 8; ++k) sum += op[(mi * 2 + ri) * 8 + k];
          int row = r0 + ri;
          if (m < 80) P.omel[(size_t)(row * 80 + m) * 400 + (tt - 1)] = sum + P.bout[m];
          else P.ogate[row * 400 + (tt - 1)] = sum + P.bg[0];
        }
      }
      if (tt < TDEC) {
        int w = tid >> 6;
        int ri = w >> 1, row = r0 + ri;
        float wl0[32], wl1[32];
#pragma unroll
        for (int f = 0; f < 32; ++f) {
          wl0[f] = P.Wl[lane * 32 + f];
          wl1[f] = P.Wl[(lane + 64) * 32 + f];
        }
        float q0 = qb[ri * 128 + lane], q1 = qb[ri * 128 + 64 + lane];
        int len = P.lens[row];
        for (int po = (w & 1); po < pc; po += 2) {
          int p = pb + po;
          float a0 = 0.f, a1 = 0.f;
#pragma unroll
          for (int f = 0; f < 32; ++f) {
            float c = conv_l[(ri * 32 + f) * 20 + po];
            a0 += c * wl0[f];
            a1 += c * wl1[f];
          }
          float e0 = tanhf(q0 + P.pmem[((size_t)row * 300 + p) * 128 + lane] + a0) * vv0;
          float e1 = tanhf(q1 + P.pmem[((size_t)row * 300 + p) * 128 + 64 + lane] + a1) * vv1;
          float es = e0 + e1;
#pragma unroll
          for (int off = 32; off > 0; off >>= 1) es += __shfl_xor(es, off, 64);
          if (lane == 0) s_rel(&P.e[row * 300 + p], (p < len) ? es : -1e9f);
        }
      }
    }
    if (tt == TDEC) break;
    rsync16(P.garr, P.grel, g, s, ++bno);  // SYNC2

    // ---- phase 3: softmax (redundant) + aw update + ctx slice ----
    {
      float* e_l = smem;  // [2][304]
      for (int i = tid; i < 600; i += 256) {
        int ri = i / 300, p = i - ri * 300;
        e_l[ri * 304 + p] = l_rel(&P.e[(r0 + ri) * 300 + p]);
      }
      __syncthreads();
      int w = tid >> 6;
      if (w < 2) {
        int ri = w;
        float mx = -3.4e38f;
        for (int i = lane; i < 300; i += 64) mx = fmaxf(mx, e_l[ri * 304 + i]);
#pragma unroll
        for (int off = 32; off > 0; off >>= 1) mx = fmaxf(mx, __shfl_xor(mx, off, 64));
        float ls = 0.f;
        for (int i = lane; i < 300; i += 64) {
          float ex = expf(e_l[ri * 304 + i] - mx);
          e_l[ri * 304 + i] = ex;
          ls += ex;
        }
#pragma unroll
        for (int off = 32; off > 0; off >>= 1) ls += __shfl_xor(ls, off, 64);
        float inv = 1.f / ls;
        for (int i = lane; i < 300; i += 64) {
          float a = e_l[ri * 304 + i] * inv;
          float2 old = aw2[ri * 330 + 15 + i];
          aw2[ri * 330 + 15 + i] = make_float2(a, old.y + a);
          if (i >= pb && i < pb + pc)
            P.oalign[((size_t)((r0 + ri) * 400 + tt)) * 300 + i] = a;
        }
      }
      __syncthreads();
      float* cpart = smem + 1024;  // [4][64]
      {
        int out = tid & 63, ch = tid >> 6;
        int ri = out >> 5, col = s * 32 + (out & 31);
        int row = r0 + ri;
        float cp = 0.f;
        const float* eb = P.enc + ((size_t)row * 300) * 512 + col;
        for (int p = ch * 75; p < ch * 75 + 75; ++p)
          cp += aw2[ri * 330 + 15 + p].x * nt_load(eb + (size_t)p * 512);
        cpart[ch * 64 + out] = cp;
      }
      __syncthreads();
      if (tid < 64) {
        int ri = tid >> 5, col = s * 32 + (tid & 31);
        float* ctxC = P.ctx + sc * 16384;
        s_rel(&ctxC[(r0 + ri) * 512 + col],
              cpart[tid] + cpart[64 + tid] + cpart[128 + tid] + cpart[192 + tid]);
      }
    }
    rsync16(P.garr, P.grel, g, s, ++bno);  // SYNC3
  }
}

// ---- host -------------------------------------------------------------------
extern "C" void kernel_launch(void* const* d_in, const int* in_sizes, int n_in,
                              void* d_out, int out_size, void* d_ws, size_t ws_size,
                              hipStream_t stream) {
  const float* enc = (const float*)d_in[0];
  const float* mels = (const float*)d_in[1];
  const int* lens = (const int*)d_in[2];
  const float* Wp0 = (const float*)d_in[3];
  const float* Wp1 = (const float*)d_in[4];
  const float* Wp2 = (const float*)d_in[5];
  const float* Wiha = (const float*)d_in[6];
  const float* Whha = (const float*)d_in[7];
  const float* biha = (const float*)d_in[8];
  const float* bhha = (const float*)d_in[9];
  const float* Wihd = (const float*)d_in[10];
  const float* Whhd = (const float*)d_in[11];
  const float* bihd = (const float*)d_in[12];
  const float* bhhd = (const float*)d_in[13];
  const float* Wq = (const float*)d_in[14];
  const float* Wm = (const float*)d_in[15];
  const float* Kloc = (const float*)d_in[16];
  const float* Wl = (const float*)d_in[17];
  const float* vv = (const float*)d_in[18];
  const float* Wout = (const float*)d_in[19];
  const float* bout = (const float*)d_in[20];
  const float* Wg = (const float*)d_in[21];
  const float* bg = (const float*)d_in[22];

  float* ws = (float*)d_ws;
  float* x_all = ws;                    // 3,276,800
  float* pmem = x_all + 3276800;        // 1,228,800
  float* ah = pmem + 1228800;           // ring4: 65,536
  float* dh = ah + 65536;               // 65,536
  float* ctx = dh + 65536;              // 65,536
  float* e = ctx + 65536;               // 9,600
  int* garr = (int*)(e + 9600);         // 8,192
  int* grel = garr + 8192;              // 512

  (void)hipMemsetAsync(ah, 0, 3 * 65536 * sizeof(float), stream);  // ah+dh+ctx all slots
  (void)hipMemsetAsync(garr, 0, (8192 + 512) * sizeof(int), stream);

  prenet_kernel<<<800, 256, 0, stream>>>(mels, Wp0, Wp1, Wp2, x_all);
  pmem_kernel<<<320, 256, 0, stream>>>(enc, Wm, pmem);

  float* omel = (float*)d_out;                  // [32][80][400]
  float* ogate = omel + 32 * 80 * 400;          // [32][400]
  float* oalign = ogate + 32 * 400;             // [32][400][300]

  DecParams P;
  P.enc = enc; P.xall = x_all; P.pmem = pmem; P.lens = lens;
  P.Wiha = Wiha; P.Whha = Whha; P.biha = biha; P.bhha = bhha;
  P.Wihd = Wihd; P.Whhd = Whhd; P.bihd = bihd; P.bhhd = bhhd;
  P.Wq = Wq; P.Kloc = Kloc; P.Wl = Wl; P.vv = vv;
  P.Wout = Wout; P.bout = bout; P.Wg = Wg; P.bg = bg;
  P.ah = ah; P.dh = dh; P.ctx = ctx; P.e = e;
  P.garr = garr; P.grel = grel;
  P.omel = omel; P.ogate = ogate; P.oalign = oalign;

  decoder_kernel<<<NBLK, 256, 0, stream>>>(P);
}

// Round 9
// 54282.397 us; speedup vs baseline: 1.3717x; 1.3717x over previous
//
#include <hip/hip_runtime.h>
#include <cstdint>

// DROP_MODE 3 = JAX partitionable threefry, bits = x0^x1  (VERIFIED r3+: absmax 0.0039)

static constexpr int TDEC = 400, TENC = 300, NMEL = 80;

__device__ __forceinline__ uint2 threefry2x32(uint32_t k0, uint32_t k1,
                                              uint32_t x0, uint32_t x1) {
  uint32_t k2 = k0 ^ k1 ^ 0x1BD11BDAu;
  x0 += k0; x1 += k1;
#define TFR(r) { x0 += x1; x1 = (x1 << (r)) | (x1 >> (32 - (r))); x1 ^= x0; }
  TFR(13) TFR(15) TFR(26) TFR(6)
  x0 += k1; x1 += k2 + 1u;
  TFR(17) TFR(29) TFR(16) TFR(24)
  x0 += k2; x1 += k0 + 2u;
  TFR(13) TFR(15) TFR(26) TFR(6)
  x0 += k0; x1 += k1 + 3u;
  TFR(17) TFR(29) TFR(16) TFR(24)
  x0 += k1; x1 += k2 + 4u;
  TFR(13) TFR(15) TFR(26) TFR(6)
  x0 += k2; x1 += k0 + 5u;
#undef TFR
  return make_uint2(x0, x1);
}

__device__ __forceinline__ bool keep_mask(uint32_t key0, uint32_t key1, uint32_t idx) {
  uint2 o = threefry2x32(key0, key1, 0u, idx);
  uint32_t bits = o.x ^ o.y;
  float u = __uint_as_float((bits >> 9) | 0x3f800000u) - 1.0f;
  return u < 0.5f;
}

__device__ __forceinline__ float dot4(float4 w, float4 a) {
  return w.x * a.x + w.y * a.y + w.z * a.z + w.w * a.w;
}
__device__ __forceinline__ float nt_load(const float* p) {
  return __builtin_nontemporal_load(p);
}

// ---- prenet (teacher-forced, all 400 steps parallel; verified) --------------
template <int K>
__device__ __forceinline__ void prenet_layer(const float* in_lds, float* out_lds,
                                             float* out_g, const float* __restrict__ W,
                                             uint32_t key0, uint32_t key1, int b0) {
  const int tid = threadIdx.x;
  const int cgp = tid & 63, bg = tid >> 6;
  float acc[4][4];
#pragma unroll
  for (int cc = 0; cc < 4; ++cc)
#pragma unroll
    for (int rr = 0; rr < 4; ++rr) acc[cc][rr] = 0.f;
  const float4* W4 = (const float4*)W;
  const float4* in4 = (const float4*)in_lds;
  for (int k4 = 0; k4 < K / 4; ++k4) {
    float4 a[4];
#pragma unroll
    for (int rr = 0; rr < 4; ++rr) a[rr] = in4[(bg * 4 + rr) * (K / 4) + k4];
#pragma unroll
    for (int cc = 0; cc < 4; ++cc) {
      float4 w = W4[(cgp + 64 * cc) * (K / 4) + k4];
#pragma unroll
      for (int rr = 0; rr < 4; ++rr) acc[cc][rr] += dot4(w, a[rr]);
    }
  }
#pragma unroll
  for (int cc = 0; cc < 4; ++cc)
#pragma unroll
    for (int rr = 0; rr < 4; ++rr) {
      int c = cgp + 64 * cc, br = bg * 4 + rr;
      float val = fmaxf(acc[cc][rr], 0.f);
      val = keep_mask(key0, key1, (uint32_t)((b0 + br) * 256 + c)) ? val * 2.f : 0.f;
      if (out_lds) out_lds[br * 256 + c] = val;
      if (out_g) out_g[(b0 + br) * 256 + c] = val;
    }
  __syncthreads();
}

__global__ __launch_bounds__(256) void prenet_kernel(const float* __restrict__ mels,
                                                     const float* __restrict__ Wp0,
                                                     const float* __restrict__ Wp1,
                                                     const float* __restrict__ Wp2,
                                                     float* __restrict__ x_all) {
  __shared__ float bufA[16 * 256];
  __shared__ float bufB[16 * 256];
  const int t = blockIdx.x >> 1, b0 = (blockIdx.x & 1) * 16;
  const int tid = threadIdx.x;
  for (int i = tid; i < 16 * 80; i += 256) {
    int br = i / 80, k = i % 80;
    bufB[br * 80 + k] = (t == 0) ? 0.f : mels[((b0 + br) * TDEC + (t - 1)) * NMEL + k];
  }
  __syncthreads();
  uint2 k0v = threefry2x32(0u, 42u, 0u, (uint32_t)(t * 3 + 0));
  uint2 k1v = threefry2x32(0u, 42u, 0u, (uint32_t)(t * 3 + 1));
  uint2 k2v = threefry2x32(0u, 42u, 0u, (uint32_t)(t * 3 + 2));
  prenet_layer<80>(bufB, bufA, nullptr, Wp0, k0v.x, k0v.y, b0);
  prenet_layer<256>(bufA, bufB, nullptr, Wp1, k1v.x, k1v.y, b0);
  prenet_layer<256>(bufB, nullptr, x_all + t * 8192, Wp2, k2v.x, k2v.y, b0);
}

// ---- pmem = enc @ Wm.T (verified) --------------------------------------------
__global__ __launch_bounds__(256) void pmem_kernel(const float* __restrict__ enc,
                                                   const float* __restrict__ Wm,
                                                   float* __restrict__ pmem) {
  const int b = blockIdx.x / 10, pc = blockIdx.x % 10;
  const int j = threadIdx.x & 127, ph = threadIdx.x >> 7;
  const float4* Wm4 = (const float4*)Wm;
  const float4* enc4 = (const float4*)enc + (size_t)(b * 300 + pc * 30 + ph * 15) * 128;
  float acc[15];
#pragma unroll
  for (int pp = 0; pp < 15; ++pp) acc[pp] = 0.f;
  for (int k4 = 0; k4 < 128; ++k4) {
    float4 w = Wm4[j * 128 + k4];
#pragma unroll
    for (int pp = 0; pp < 15; ++pp) acc[pp] += dot4(w, enc4[pp * 128 + k4]);
  }
#pragma unroll
  for (int pp = 0; pp < 15; ++pp)
    pmem[(size_t)(b * 300 + pc * 30 + ph * 15 + pp) * 128 + j] = acc[pp];
}

// ---- shared param block -------------------------------------------------------
struct GP {
  const float *xall, *enc, *pmem;
  const int* lens;
  const float *Wiha, *Whha, *biha, *bhha;
  const float *Wihd, *Whhd, *bihd, *bhhd;
  const float *Wq, *Kloc, *Wl, *vv, *Wout, *bout, *Wg, *bg;
  float *ah, *dh, *ctx, *aw, *awsum, *e;  // ah/dh/ctx: [2][32][512] ping-pong
  float *omel, *ogate, *oalign;
};

// ---- K1: batched GRU slice (r3-verified math, plain stores) -------------------
template <int KIN>
__device__ __forceinline__ void gru_phase(const float4* __restrict__ A4, int a4n,
                                          const float4* __restrict__ B4,
                                          const float4* __restrict__ H4,
                                          const float* __restrict__ Wih,
                                          const float* __restrict__ Whh,
                                          const float* __restrict__ bih,
                                          const float* __restrict__ bhh,
                                          const float* __restrict__ hprev,
                                          float* __restrict__ hout,
                                          int idx0, float* lds) {
  const int tid = threadIdx.x;
  const int row = tid >> 3, seg = tid & 7;
  constexpr int K4I = KIN / 4;
  constexpr int SI = K4I / 8;
  const float4* Wih4 = (const float4*)Wih;
  const float4* Whh4 = (const float4*)Whh;
  float acc[24];
#pragma unroll
  for (int g = 0; g < 24; ++g) acc[g] = 0.f;
  for (int s = 0; s < SI; ++s) {
    int k4 = seg * SI + s;
    float4 a = (k4 < a4n) ? A4[row * a4n + k4] : B4[row * 128 + (k4 - a4n)];
#pragma unroll
    for (int gate = 0; gate < 3; ++gate)
#pragma unroll
      for (int i = 0; i < 4; ++i)
        acc[gate * 4 + i] += dot4(Wih4[(size_t)(gate * 512 + idx0 + i) * K4I + k4], a);
  }
  for (int s = 0; s < 16; ++s) {
    int k4 = seg * 16 + s;
    float4 a = H4[row * 128 + k4];
#pragma unroll
    for (int gate = 0; gate < 3; ++gate)
#pragma unroll
      for (int i = 0; i < 4; ++i)
        acc[12 + gate * 4 + i] += dot4(Whh4[(size_t)(gate * 512 + idx0 + i) * 128 + k4], a);
  }
#pragma unroll
  for (int g = 0; g < 24; ++g) lds[(g * 32 + row) * 8 + seg] = acc[g];
  __syncthreads();
  if (tid < 128) {
    int i = tid >> 5, r = tid & 31;
    float gi[3], gh[3];
#pragma unroll
    for (int gate = 0; gate < 3; ++gate) {
      float si = 0.f, sh = 0.f;
#pragma unroll
      for (int s = 0; s < 8; ++s) {
        si += lds[((gate * 4 + i) * 32 + r) * 8 + s];
        sh += lds[((12 + gate * 4 + i) * 32 + r) * 8 + s];
      }
      gi[gate] = si + bih[gate * 512 + idx0 + i];
      gh[gate] = sh + bhh[gate * 512 + idx0 + i];
    }
    float rr = 1.f / (1.f + expf(-(gi[0] + gh[0])));
    float zz = 1.f / (1.f + expf(-(gi[1] + gh[1])));
    float nn = tanhf(gi[2] + rr * gh[2]);
    float hp = hprev[r * 512 + idx0 + i];
    hout[r * 512 + idx0 + i] = (1.f - zz) * nn + zz * hp;
  }
}

__global__ __launch_bounds__(256) void k_gru(GP P, int t) {
  __shared__ float lds[6144];
  const int blk = blockIdx.x;
  const int p0 = t & 1, p1 = p0 ^ 1;
  if (blk < 128) {
    if (t < TDEC)
      gru_phase<768>((const float4*)(P.xall + (size_t)t * 8192), 64,
                     (const float4*)(P.ctx + p1 * 16384),
                     (const float4*)(P.ah + p1 * 16384),
                     P.Wiha, P.Whha, P.biha, P.bhha,
                     P.ah + p1 * 16384, P.ah + p0 * 16384, blk * 4, lds);
  } else {
    if (t >= 1)
      gru_phase<1024>((const float4*)(P.ah + p1 * 16384), 128,
                      (const float4*)(P.ctx + p1 * 16384),
                      (const float4*)(P.dh + p0 * 16384),
                      P.Wihd, P.Whhd, P.bihd, P.bhhd,
                      P.dh + p0 * 16384, P.dh + p1 * 16384, (blk - 128) * 4, lds);
  }
}

// ---- K2: q-proj + location conv + energies, per (row, 75-pos quarter) --------
__global__ __launch_bounds__(256) void k_energy(GP P, int t) {
  __shared__ float smem[5056];
  float* qp = smem;           // 256
  float* qb = smem + 256;     // 128
  float* awW = smem + 384;    // 112
  float* asW = smem + 496;    // 112
  float2* t2f = (float2*)(smem + 608);  // 992 f2 (1984)
  float* convl = smem + 2592; // 32*76 = 2432
  const int tid = threadIdx.x;
  const int r = blockIdx.x >> 2, q = blockIdx.x & 3;
  const int p0 = t & 1;
  const int pbase = q * 75;

  // taps
  for (int i = tid; i < 992; i += 256) {
    int f = i / 31, k = i % 31;
    t2f[i] = make_float2(P.Kloc[f * 62 + k], P.Kloc[f * 62 + 31 + k]);
  }
  // aw/awsum window with halo 15
  for (int i = tid; i < 105; i += 256) {
    int p = pbase - 15 + i;
    bool ok = (p >= 0 && p < TENC);
    awW[i] = ok ? P.aw[r * 300 + p] : 0.f;
    asW[i] = ok ? P.awsum[r * 300 + p] : 0.f;
  }
  // q-proj (redundant per block): q[128] = Wq . ah_t[r]
  {
    int j = tid & 127, kh = tid >> 7;
    const float4* Wq4 = (const float4*)P.Wq;
    const float4* a4 = (const float4*)(P.ah + p0 * 16384 + r * 512);
    float acc = 0.f;
    for (int k4 = kh * 64; k4 < kh * 64 + 64; ++k4) acc += dot4(Wq4[j * 128 + k4], a4[k4]);
    qp[j * 2 + kh] = acc;
  }
  __syncthreads();
  if (tid < 128) qb[tid] = qp[tid * 2] + qp[tid * 2 + 1];
  // conv: f = tid&31, 8 p-lanes
  {
    int f = tid & 31, pl0 = tid >> 5;
    for (int pl = pl0; pl < 75; pl += 8) {
      float a = 0.f;
#pragma unroll
      for (int k = 0; k < 31; ++k) {
        float2 tv = t2f[f * 31 + k];
        a += awW[pl + k] * tv.x + asW[pl + k] * tv.y;
      }
      convl[f * 76 + pl] = a;
    }
  }
  __syncthreads();
  // energies
  {
    int w = tid >> 6, lane = tid & 63;
    float wl0[32], wl1[32];
#pragma unroll
    for (int f = 0; f < 32; ++f) {
      wl0[f] = P.Wl[lane * 32 + f];
      wl1[f] = P.Wl[(lane + 64) * 32 + f];
    }
    float v0 = P.vv[lane], v1 = P.vv[lane + 64];
    float q0 = qb[lane], q1 = qb[lane + 64];
    int len = P.lens[r];
    for (int pl = w; pl < 75; pl += 4) {
      int p = pbase + pl;
      float a0 = 0.f, a1 = 0.f;
#pragma unroll
      for (int f = 0; f < 32; ++f) {
        float c = convl[f * 76 + pl];
        a0 += c * wl0[f];
        a1 += c * wl1[f];
      }
      float e0 = tanhf(q0 + P.pmem[((size_t)r * 300 + p) * 128 + lane] + a0) * v0;
      float e1 = tanhf(q1 + P.pmem[((size_t)r * 300 + p) * 128 + 64 + lane] + a1) * v1;
      float es = e0 + e1;
#pragma unroll
      for (int off = 32; off > 0; off >>= 1) es += __shfl_xor(es, off, 64);
      if (lane == 0) P.e[r * 304 + p] = (p < len) ? es : -1e9f;
    }
  }
}

// ---- K3: softmax + aw/awsum + oalign + ctx + outproj_{t-1}, per row ----------
__global__ __launch_bounds__(512) void k_ctx(GP P, int t) {
  __shared__ float smem[1520];
  float* e_l = smem;          // 304
  float* red = smem + 304;    // 8
  float* dhcx = smem + 312;   // 1024
  float* opl = smem + 1336;   // 168
  const int tid = threadIdx.x;
  const int r = blockIdx.x;
  const int p0 = t & 1, p1 = p0 ^ 1;
  const int w = tid >> 6, lane = tid & 63;

  // stage dh_{t-1} | ctx_{t-1} for outproj
  if (t >= 1) {
    for (int i = tid; i < 512; i += 512) {
      dhcx[i] = P.dh[p1 * 16384 + r * 512 + i];
      dhcx[512 + i] = P.ctx[p1 * 16384 + r * 512 + i];
    }
  }
  if (t < TDEC) {
    if (tid < 300) e_l[tid] = P.e[r * 304 + tid];
    if (tid >= 300 && tid < 304) e_l[tid] = -3.4e38f;
  }
  __syncthreads();

  if (t < TDEC) {
    // softmax over 300
    float mx = (tid < 304) ? e_l[tid] : -3.4e38f;
#pragma unroll
    for (int off = 32; off > 0; off >>= 1) mx = fmaxf(mx, __shfl_xor(mx, off, 64));
    if (lane == 0) red[w] = mx;
    __syncthreads();
    mx = red[0];
#pragma unroll
    for (int k = 1; k < 8; ++k) mx = fmaxf(mx, red[k]);
    __syncthreads();
    float ex = 0.f;
    if (tid < 300) {
      ex = expf(e_l[tid] - mx);
      e_l[tid] = ex;
    }
    float ls = ex;
#pragma unroll
    for (int off = 32; off > 0; off >>= 1) ls += __shfl_xor(ls, off, 64);
    if (lane == 0) red[w] = ls;
    __syncthreads();
    float tot = red[0];
#pragma unroll
    for (int k = 1; k < 8; ++k) tot += red[k];
    float inv = 1.f / tot;
    if (tid < 300) {
      float a = e_l[tid] * inv;
      e_l[tid] = a;
      P.aw[r * 300 + tid] = a;
      P.awsum[r * 300 + tid] += a;
      P.oalign[((size_t)(r * 400 + t)) * 300 + tid] = a;
    }
    __syncthreads();
  }

  // outproj for step t-1 (all 512 threads; independent of softmax result)
  if (t >= 1) {
    if (tid < 162) {
      int m = tid >> 1, h = tid & 1;
      const float4* W4 = (m < 80) ? ((const float4*)P.Wout + (size_t)m * 256)
                                  : (const float4*)P.Wg;
      const float4* x4 = (const float4*)dhcx;
      float a = 0.f;
      for (int k4 = h * 128; k4 < h * 128 + 128; ++k4) a += dot4(W4[k4], x4[k4]);
      opl[tid] = a;
    }
    __syncthreads();
    if (tid < 81) {
      float sum = opl[tid * 2] + opl[tid * 2 + 1];
      if (tid < 80) P.omel[(size_t)(r * 80 + tid) * 400 + (t - 1)] = sum + P.bout[tid];
      else P.ogate[r * 400 + (t - 1)] = sum + P.bg[0];
    }
  }

  // ctx_t: one col per thread, enc NT-streamed
  if (t < TDEC) {
    float acc = 0.f;
    const float* eb = P.enc + ((size_t)r * 300) * 512 + tid;
    for (int p = 0; p < TENC; ++p) acc += e_l[p] * nt_load(eb + (size_t)p * 512);
    P.ctx[p0 * 16384 + r * 512 + tid] = acc;
  }
}

// ---- host ---------------------------------------------------------------------
extern "C" void kernel_launch(void* const* d_in, const int* in_sizes, int n_in,
                              void* d_out, int out_size, void* d_ws, size_t ws_size,
                              hipStream_t stream) {
  const float* enc = (const float*)d_in[0];
  const float* mels = (const float*)d_in[1];
  const int* lens = (const int*)d_in[2];
  const float* Wp0 = (const float*)d_in[3];
  const float* Wp1 = (const float*)d_in[4];
  const float* Wp2 = (const float*)d_in[5];

  float* ws = (float*)d_ws;
  float* x_all = ws;                    // 3,276,800
  float* pmem = x_all + 3276800;        // 1,228,800
  float* ah = pmem + 1228800;           // 2*16384 = 32,768
  float* dh = ah + 32768;               // 32,768
  float* ctx = dh + 32768;              // 32,768
  float* aw = ctx + 32768;              // 9,600
  float* awsum = aw + 9600;             // 9,600
  float* e = awsum + 9600;              // 32*304 = 9,728

  // zero all mutable state (both parities + aw/awsum/e)
  (void)hipMemsetAsync(ah, 0, (3 * 32768 + 9600 + 9600 + 9728) * sizeof(float), stream);

  prenet_kernel<<<800, 256, 0, stream>>>(mels, Wp0, Wp1, Wp2, x_all);
  pmem_kernel<<<320, 256, 0, stream>>>(enc, (const float*)d_in[15], pmem);

  float* omel = (float*)d_out;                  // [32][80][400]
  float* ogate = omel + 32 * 80 * 400;          // [32][400]
  float* oalign = ogate + 32 * 400;             // [32][400][300]

  GP P;
  P.xall = x_all; P.enc = enc; P.pmem = pmem; P.lens = lens;
  P.Wiha = (const float*)d_in[6]; P.Whha = (const float*)d_in[7];
  P.biha = (const float*)d_in[8]; P.bhha = (const float*)d_in[9];
  P.Wihd = (const float*)d_in[10]; P.Whhd = (const float*)d_in[11];
  P.bihd = (const float*)d_in[12]; P.bhhd = (const float*)d_in[13];
  P.Wq = (const float*)d_in[14]; P.Kloc = (const float*)d_in[16];
  P.Wl = (const float*)d_in[17]; P.vv = (const float*)d_in[18];
  P.Wout = (const float*)d_in[19]; P.bout = (const float*)d_in[20];
  P.Wg = (const float*)d_in[21]; P.bg = (const float*)d_in[22];
  P.ah = ah; P.dh = dh; P.ctx = ctx; P.aw = aw; P.awsum = awsum; P.e = e;
  P.omel = omel; P.ogate = ogate; P.oalign = oalign;

  for (int t = 0; t <= TDEC; ++t) {
    k_gru<<<256, 256, 0, stream>>>(P, t);
    if (t < TDEC) k_energy<<<128, 256, 0, stream>>>(P, t);
    k_ctx<<<32, 512, 0, stream>>>(P, t);
  }
}

// Round 11
// 45764.984 us; speedup vs baseline: 1.6270x; 1.1861x over previous
//
#include <hip/hip_runtime.h>
#include <cstdint>

// DROP_MODE 3 = JAX partitionable threefry, bits = x0^x1  (VERIFIED r3+: absmax 0.0039)

static constexpr int TDEC = 400, TENC = 300, NMEL = 80;

__device__ __forceinline__ uint2 threefry2x32(uint32_t k0, uint32_t k1,
                                              uint32_t x0, uint32_t x1) {
  uint32_t k2 = k0 ^ k1 ^ 0x1BD11BDAu;
  x0 += k0; x1 += k1;
#define TFR(r) { x0 += x1; x1 = (x1 << (r)) | (x1 >> (32 - (r))); x1 ^= x0; }
  TFR(13) TFR(15) TFR(26) TFR(6)
  x0 += k1; x1 += k2 + 1u;
  TFR(17) TFR(29) TFR(16) TFR(24)
  x0 += k2; x1 += k0 + 2u;
  TFR(13) TFR(15) TFR(26) TFR(6)
  x0 += k0; x1 += k1 + 3u;
  TFR(17) TFR(29) TFR(16) TFR(24)
  x0 += k1; x1 += k2 + 4u;
  TFR(13) TFR(15) TFR(26) TFR(6)
  x0 += k2; x1 += k0 + 5u;
#undef TFR
  return make_uint2(x0, x1);
}

__device__ __forceinline__ bool keep_mask(uint32_t key0, uint32_t key1, uint32_t idx) {
  uint2 o = threefry2x32(key0, key1, 0u, idx);
  uint32_t bits = o.x ^ o.y;
  float u = __uint_as_float((bits >> 9) | 0x3f800000u) - 1.0f;
  return u < 0.5f;
}

__device__ __forceinline__ float dot4(float4 w, float4 a) {
  return w.x * a.x + w.y * a.y + w.z * a.z + w.w * a.w;
}
__device__ __forceinline__ float nt_load(const float* p) {
  return __builtin_nontemporal_load(p);
}

// ---- prenet (teacher-forced, all 400 steps parallel; verified) --------------
template <int K>
__device__ __forceinline__ void prenet_layer(const float* in_lds, float* out_lds,
                                             float* out_g, const float* __restrict__ W,
                                             uint32_t key0, uint32_t key1, int b0) {
  const int tid = threadIdx.x;
  const int cgp = tid & 63, bg = tid >> 6;
  float acc[4][4];
#pragma unroll
  for (int cc = 0; cc < 4; ++cc)
#pragma unroll
    for (int rr = 0; rr < 4; ++rr) acc[cc][rr] = 0.f;
  const float4* W4 = (const float4*)W;
  const float4* in4 = (const float4*)in_lds;
  for (int k4 = 0; k4 < K / 4; ++k4) {
    float4 a[4];
#pragma unroll
    for (int rr = 0; rr < 4; ++rr) a[rr] = in4[(bg * 4 + rr) * (K / 4) + k4];
#pragma unroll
    for (int cc = 0; cc < 4; ++cc) {
      float4 w = W4[(cgp + 64 * cc) * (K / 4) + k4];
#pragma unroll
      for (int rr = 0; rr < 4; ++rr) acc[cc][rr] += dot4(w, a[rr]);
    }
  }
#pragma unroll
  for (int cc = 0; cc < 4; ++cc)
#pragma unroll
    for (int rr = 0; rr < 4; ++rr) {
      int c = cgp + 64 * cc, br = bg * 4 + rr;
      float val = fmaxf(acc[cc][rr], 0.f);
      val = keep_mask(key0, key1, (uint32_t)((b0 + br) * 256 + c)) ? val * 2.f : 0.f;
      if (out_lds) out_lds[br * 256 + c] = val;
      if (out_g) out_g[(b0 + br) * 256 + c] = val;
    }
  __syncthreads();
}

__global__ __launch_bounds__(256) void prenet_kernel(const float* __restrict__ mels,
                                                     const float* __restrict__ Wp0,
                                                     const float* __restrict__ Wp1,
                                                     const float* __restrict__ Wp2,
                                                     float* __restrict__ x_all) {
  __shared__ float bufA[16 * 256];
  __shared__ float bufB[16 * 256];
  const int t = blockIdx.x >> 1, b0 = (blockIdx.x & 1) * 16;
  const int tid = threadIdx.x;
  for (int i = tid; i < 16 * 80; i += 256) {
    int br = i / 80, k = i % 80;
    bufB[br * 80 + k] = (t == 0) ? 0.f : mels[((b0 + br) * TDEC + (t - 1)) * NMEL + k];
  }
  __syncthreads();
  uint2 k0v = threefry2x32(0u, 42u, 0u, (uint32_t)(t * 3 + 0));
  uint2 k1v = threefry2x32(0u, 42u, 0u, (uint32_t)(t * 3 + 1));
  uint2 k2v = threefry2x32(0u, 42u, 0u, (uint32_t)(t * 3 + 2));
  prenet_layer<80>(bufB, bufA, nullptr, Wp0, k0v.x, k0v.y, b0);
  prenet_layer<256>(bufA, bufB, nullptr, Wp1, k1v.x, k1v.y, b0);
  prenet_layer<256>(bufB, nullptr, x_all + t * 8192, Wp2, k2v.x, k2v.y, b0);
}

// ---- pmem = enc @ Wm.T (verified) --------------------------------------------
__global__ __launch_bounds__(256) void pmem_kernel(const float* __restrict__ enc,
                                                   const float* __restrict__ Wm,
                                                   float* __restrict__ pmem) {
  const int b = blockIdx.x / 10, pc = blockIdx.x % 10;
  const int j = threadIdx.x & 127, ph = threadIdx.x >> 7;
  const float4* Wm4 = (const float4*)Wm;
  const float4* enc4 = (const float4*)enc + (size_t)(b * 300 + pc * 30 + ph * 15) * 128;
  float acc[15];
#pragma unroll
  for (int pp = 0; pp < 15; ++pp) acc[pp] = 0.f;
  for (int k4 = 0; k4 < 128; ++k4) {
    float4 w = Wm4[j * 128 + k4];
#pragma unroll
    for (int pp = 0; pp < 15; ++pp) acc[pp] += dot4(w, enc4[pp * 128 + k4]);
  }
#pragma unroll
  for (int pp = 0; pp < 15; ++pp)
    pmem[(size_t)(b * 300 + pc * 30 + ph * 15 + pp) * 128 + j] = acc[pp];
}

// ---- shared param block -------------------------------------------------------
struct GP {
  const float *xall, *enc, *pmem;
  const int* lens;
  const float *Wiha, *Whha, *biha, *bhha;
  const float *Wihd, *Whhd, *bihd, *bhhd;
  const float *Wq, *Kloc, *Wl, *vv, *Wout, *bout, *Wg, *bg;
  float *ah, *dh, *ctx, *aw, *awsum, *e;  // ah/dh/ctx: [2][32][512] ping-pong
  float *omel, *ogate, *oalign;
};

// ---- K1: batched GRU slice (r3-verified math) --------------------------------
template <int KIN>
__device__ __forceinline__ void gru_phase(const float4* __restrict__ A4, int a4n,
                                          const float4* __restrict__ B4,
                                          const float4* __restrict__ H4,
                                          const float* __restrict__ Wih,
                                          const float* __restrict__ Whh,
                                          const float* __restrict__ bih,
                                          const float* __restrict__ bhh,
                                          const float* __restrict__ hprev,
                                          float* __restrict__ hout,
                                          int idx0, float* lds) {
  const int tid = threadIdx.x;
  const int row = tid >> 3, seg = tid & 7;
  constexpr int K4I = KIN / 4;
  constexpr int SI = K4I / 8;
  const float4* Wih4 = (const float4*)Wih;
  const float4* Whh4 = (const float4*)Whh;
  float acc[24];
#pragma unroll
  for (int g = 0; g < 24; ++g) acc[g] = 0.f;
  for (int s = 0; s < SI; ++s) {
    int k4 = seg * SI + s;
    float4 a = (k4 < a4n) ? A4[row * a4n + k4] : B4[row * 128 + (k4 - a4n)];
#pragma unroll
    for (int gate = 0; gate < 3; ++gate)
#pragma unroll
      for (int i = 0; i < 4; ++i)
        acc[gate * 4 + i] += dot4(Wih4[(size_t)(gate * 512 + idx0 + i) * K4I + k4], a);
  }
  for (int s = 0; s < 16; ++s) {
    int k4 = seg * 16 + s;
    float4 a = H4[row * 128 + k4];
#pragma unroll
    for (int gate = 0; gate < 3; ++gate)
#pragma unroll
      for (int i = 0; i < 4; ++i)
        acc[12 + gate * 4 + i] += dot4(Whh4[(size_t)(gate * 512 + idx0 + i) * 128 + k4], a);
  }
#pragma unroll
  for (int g = 0; g < 24; ++g) lds[(g * 32 + row) * 8 + seg] = acc[g];
  __syncthreads();
  if (tid < 128) {
    int i = tid >> 5, r = tid & 31;
    float gi[3], gh[3];
#pragma unroll
    for (int gate = 0; gate < 3; ++gate) {
      float si = 0.f, sh = 0.f;
#pragma unroll
      for (int s = 0; s < 8; ++s) {
        si += lds[((gate * 4 + i) * 32 + r) * 8 + s];
        sh += lds[((12 + gate * 4 + i) * 32 + r) * 8 + s];
      }
      gi[gate] = si + bih[gate * 512 + idx0 + i];
      gh[gate] = sh + bhh[gate * 512 + idx0 + i];
    }
    float rr = 1.f / (1.f + expf(-(gi[0] + gh[0])));
    float zz = 1.f / (1.f + expf(-(gi[1] + gh[1])));
    float nn = tanhf(gi[2] + rr * gh[2]);
    float hp = hprev[r * 512 + idx0 + i];
    hout[r * 512 + idx0 + i] = (1.f - zz) * nn + zz * hp;
  }
}

__global__ __launch_bounds__(256) void k_gru(GP P, int t) {
  __shared__ float lds[6144];
  const int blk = blockIdx.x;
  const int p0 = t & 1, p1 = p0 ^ 1;
  if (blk < 128) {
    if (t < TDEC)
      gru_phase<768>((const float4*)(P.xall + (size_t)t * 8192), 64,
                     (const float4*)(P.ctx + p1 * 16384),
                     (const float4*)(P.ah + p1 * 16384),
                     P.Wiha, P.Whha, P.biha, P.bhha,
                     P.ah + p1 * 16384, P.ah + p0 * 16384, blk * 4, lds);
  } else {
    if (t >= 1)
      gru_phase<1024>((const float4*)(P.ah + p1 * 16384), 128,
                      (const float4*)(P.ctx + p1 * 16384),
                      (const float4*)(P.dh + p0 * 16384),
                      P.Wihd, P.Whhd, P.bihd, P.bhhd,
                      P.dh + p0 * 16384, P.dh + p1 * 16384, (blk - 128) * 4, lds);
  }
}

// ---- K2: energies (blk<128, per row-quarter) + outproj_{t-1} (blk 128..159) --
__global__ __launch_bounds__(256) void k_energy(GP P, int t) {
  __shared__ float smem[5056];
  const int tid = threadIdx.x;
  const int blk = blockIdx.x;
  const int p0 = t & 1, p1 = p0 ^ 1;

  if (blk >= 128) {  // ---- outproj for step t-1, one block per row ----
    if (t < 1) return;
    const int r = blk - 128;
    float* dhcx = smem;       // 1024
    float* opl = smem + 1024; // 162
    for (int i = tid; i < 512; i += 256) {
      dhcx[i] = P.dh[p1 * 16384 + r * 512 + i];
      dhcx[512 + i] = P.ctx[p1 * 16384 + r * 512 + i];
    }
    __syncthreads();
    if (tid < 162) {
      int m = tid >> 1, h = tid & 1;
      const float4* W4 = (m < 80) ? ((const float4*)P.Wout + (size_t)m * 256)
                                  : (const float4*)P.Wg;
      const float4* x4 = (const float4*)dhcx;
      float a = 0.f;
      for (int k4 = h * 128; k4 < h * 128 + 128; ++k4) a += dot4(W4[k4], x4[k4]);
      opl[tid] = a;
    }
    __syncthreads();
    if (tid < 81) {
      float sum = opl[tid * 2] + opl[tid * 2 + 1];
      if (tid < 80) P.omel[(size_t)(r * 80 + tid) * 400 + (t - 1)] = sum + P.bout[tid];
      else P.ogate[r * 400 + (t - 1)] = sum + P.bg[0];
    }
    return;
  }

  // ---- energies for (row, 75-pos quarter) ----
  if (t >= TDEC) return;
  float* qp = smem;           // 256
  float* qb = smem + 256;     // 128
  float* awW = smem + 384;    // 112
  float* asW = smem + 496;    // 112
  float2* t2f = (float2*)(smem + 608);  // 992 f2
  float* convl = smem + 2592; // 32*76
  const int r = blk >> 2, q = blk & 3;
  const int pbase = q * 75;

  for (int i = tid; i < 992; i += 256) {
    int f = i / 31, k = i % 31;
    t2f[i] = make_float2(P.Kloc[f * 62 + k], P.Kloc[f * 62 + 31 + k]);
  }
  for (int i = tid; i < 105; i += 256) {
    int p = pbase - 15 + i;
    bool ok = (p >= 0 && p < TENC);
    awW[i] = ok ? P.aw[r * 300 + p] : 0.f;
    asW[i] = ok ? P.awsum[r * 300 + p] : 0.f;
  }
  {
    int j = tid & 127, kh = tid >> 7;
    const float4* Wq4 = (const float4*)P.Wq;
    const float4* a4 = (const float4*)(P.ah + p0 * 16384 + r * 512);
    float acc = 0.f;
    for (int k4 = kh * 64; k4 < kh * 64 + 64; ++k4) acc += dot4(Wq4[j * 128 + k4], a4[k4]);
    qp[j * 2 + kh] = acc;
  }
  __syncthreads();
  if (tid < 128) qb[tid] = qp[tid * 2] + qp[tid * 2 + 1];
  {
    int f = tid & 31, pl0 = tid >> 5;
    for (int pl = pl0; pl < 75; pl += 8) {
      float a = 0.f;
#pragma unroll
      for (int k = 0; k < 31; ++k) {
        float2 tv = t2f[f * 31 + k];
        a += awW[pl + k] * tv.x + asW[pl + k] * tv.y;
      }
      convl[f * 76 + pl] = a;
    }
  }
  __syncthreads();
  {
    int w = tid >> 6, lane = tid & 63;
    float wl0[32], wl1[32];
#pragma unroll
    for (int f = 0; f < 32; ++f) {
      wl0[f] = P.Wl[lane * 32 + f];
      wl1[f] = P.Wl[(lane + 64) * 32 + f];
    }
    float v0 = P.vv[lane], v1 = P.vv[lane + 64];
    float q0 = qb[lane], q1 = qb[lane + 64];
    int len = P.lens[r];
    for (int pl = w; pl < 75; pl += 4) {
      int p = pbase + pl;
      float a0 = 0.f, a1 = 0.f;
#pragma unroll
      for (int f = 0; f < 32; ++f) {
        float c = convl[f * 76 + pl];
        a0 += c * wl0[f];
        a1 += c * wl1[f];
      }
      float e0 = tanhf(q0 + P.pmem[((size_t)r * 300 + p) * 128 + lane] + a0) * v0;
      float e1 = tanhf(q1 + P.pmem[((size_t)r * 300 + p) * 128 + 64 + lane] + a1) * v1;
      float es = e0 + e1;
#pragma unroll
      for (int off = 32; off > 0; off >>= 1) es += __shfl_xor(es, off, 64);
      if (lane == 0) P.e[r * 304 + p] = (p < len) ? es : -1e9f;
    }
  }
}

// ---- K3: softmax (redundant per 8 blocks/row) + aw/awsum + oalign + ctx slice --
__global__ __launch_bounds__(256) void k_ctx(GP P, int t) {
  __shared__ float smem[600];
  float* e_l = smem;          // 304
  float* red = smem + 304;    // 8
  float* cpart = smem + 320;  // 256
  const int tid = threadIdx.x;
  const int r = blockIdx.x >> 3, s8 = blockIdx.x & 7;
  const int p0 = t & 1;
  const int w = tid >> 6, lane = tid & 63;

  // FIX r11: 256-thread staging must be strided (r10 left e_l[256..303] garbage)
  for (int i = tid; i < 300; i += 256) e_l[i] = P.e[r * 304 + i];
  if (tid < 4) e_l[300 + tid] = -3.4e38f;
  __syncthreads();

  // softmax over 300 (4 waves)
  float mx = -3.4e38f;
  for (int i = tid; i < 304; i += 256) mx = fmaxf(mx, e_l[i]);
#pragma unroll
  for (int off = 32; off > 0; off >>= 1) mx = fmaxf(mx, __shfl_xor(mx, off, 64));
  if (lane == 0) red[w] = mx;
  __syncthreads();
  mx = fmaxf(fmaxf(red[0], red[1]), fmaxf(red[2], red[3]));
  __syncthreads();
  float ls = 0.f;
  for (int i = tid; i < 300; i += 256) {
    float ex = expf(e_l[i] - mx);
    e_l[i] = ex;
    ls += ex;
  }
#pragma unroll
  for (int off = 32; off > 0; off >>= 1) ls += __shfl_xor(ls, off, 64);
  if (lane == 0) red[w] = ls;
  __syncthreads();
  float inv = 1.f / (red[0] + red[1] + red[2] + red[3]);
  for (int i = tid; i < 300; i += 256) {
    float a = e_l[i] * inv;
    e_l[i] = a;
    if (s8 == 0) {
      P.aw[r * 300 + i] = a;
      P.awsum[r * 300 + i] += a;
      P.oalign[((size_t)(r * 400 + t)) * 300 + i] = a;
    }
  }
  __syncthreads();

  // ctx slice: 64 cols, 4 chunks of 75 positions, enc NT-streamed
  {
    int j = tid & 63, pc = tid >> 6;
    float cp = 0.f;
    const float* eb = P.enc + ((size_t)r * 300) * 512 + s8 * 64 + j;
    for (int p = pc * 75; p < pc * 75 + 75; ++p)
      cp += e_l[p] * nt_load(eb + (size_t)p * 512);
    cpart[pc * 64 + j] = cp;
  }
  __syncthreads();
  if (tid < 64)
    P.ctx[p0 * 16384 + r * 512 + s8 * 64 + tid] =
        cpart[tid] + cpart[64 + tid] + cpart[128 + tid] + cpart[192 + tid];
}

// ---- host ---------------------------------------------------------------------
extern "C" void kernel_launch(void* const* d_in, const int* in_sizes, int n_in,
                              void* d_out, int out_size, void* d_ws, size_t ws_size,
                              hipStream_t stream) {
  const float* enc = (const float*)d_in[0];
  const float* mels = (const float*)d_in[1];
  const int* lens = (const int*)d_in[2];
  const float* Wp0 = (const float*)d_in[3];
  const float* Wp1 = (const float*)d_in[4];
  const float* Wp2 = (const float*)d_in[5];

  float* ws = (float*)d_ws;
  float* x_all = ws;                    // 3,276,800
  float* pmem = x_all + 3276800;        // 1,228,800
  float* ah = pmem + 1228800;           // 2*16384
  float* dh = ah + 32768;
  float* ctx = dh + 32768;
  float* aw = ctx + 32768;              // 9,600
  float* awsum = aw + 9600;             // 9,600
  float* e = awsum + 9600;              // 32*304

  (void)hipMemsetAsync(ah, 0, (3 * 32768 + 9600 + 9600 + 9728) * sizeof(float), stream);

  prenet_kernel<<<800, 256, 0, stream>>>(mels, Wp0, Wp1, Wp2, x_all);
  pmem_kernel<<<320, 256, 0, stream>>>(enc, (const float*)d_in[15], pmem);

  float* omel = (float*)d_out;                  // [32][80][400]
  float* ogate = omel + 32 * 80 * 400;          // [32][400]
  float* oalign = ogate + 32 * 400;             // [32][400][300]

  GP P;
  P.xall = x_all; P.enc = enc; P.pmem = pmem; P.lens = lens;
  P.Wiha = (const float*)d_in[6]; P.Whha = (const float*)d_in[7];
  P.biha = (const float*)d_in[8]; P.bhha = (const float*)d_in[9];
  P.Wihd = (const float*)d_in[10]; P.Whhd = (const float*)d_in[11];
  P.bihd = (const float*)d_in[12]; P.bhhd = (const float*)d_in[13];
  P.Wq = (const float*)d_in[14]; P.Kloc = (const float*)d_in[16];
  P.Wl = (const float*)d_in[17]; P.vv = (const float*)d_in[18];
  P.Wout = (const float*)d_in[19]; P.bout = (const float*)d_in[20];
  P.Wg = (const float*)d_in[21]; P.bg = (const float*)d_in[22];
  P.ah = ah; P.dh = dh; P.ctx = ctx; P.aw = aw; P.awsum = awsum; P.e = e;
  P.omel = omel; P.ogate = ogate; P.oalign = oalign;

  for (int t = 0; t <= TDEC; ++t) {
    k_gru<<<256, 256, 0, stream>>>(P, t);
    k_energy<<<160, 256, 0, stream>>>(P, t);
    if (t < TDEC) k_ctx<<<256, 256, 0, stream>>>(P, t);
  }
}